// Round 6
// baseline (201.793 us; speedup 1.0000x reference)
//
#include <hip/hip_runtime.h>

#define T_DIM 2048
#define C_DIM 768
#define NH    12
#define HD    64
#define KDIM  768
#define NJOBS (24 * 32)

typedef __attribute__((ext_vector_type(8))) short short8;
typedef __attribute__((ext_vector_type(4))) float f32x4;
typedef unsigned short u16;

__device__ __forceinline__ u16 f2bf(float f) {
    unsigned int u = __builtin_bit_cast(unsigned int, f);
    u = (u + 0x7fffu + ((u >> 16) & 1u)) >> 16;   // RNE
    return (u16)u;
}
__device__ __forceinline__ f32x4 max4(f32x4 a, f32x4 b) {
    f32x4 r; r[0]=fmaxf(a[0],b[0]); r[1]=fmaxf(a[1],b[1]);
    r[2]=fmaxf(a[2],b[2]); r[3]=fmaxf(a[3],b[3]); return r;
}
__device__ __forceinline__ unsigned int cvtpk(float a, float b) {
    unsigned int r;
    asm("v_cvt_pk_bf16_f32 %0, %1, %2" : "=v"(r) : "v"(a), "v"(b));
    return r;
}
__device__ __forceinline__ uint4 pack8(float4 a, float4 b) {
    return make_uint4(cvtpk(a.x, a.y), cvtpk(a.z, a.w),
                      cvtpk(b.x, b.y), cvtpk(b.z, b.w));
}

// ---------------------------------------------------------------------------
// fp32 -> bf16 conversion of W_attn, W_proj only (x folded into gemm_qkv).
// Also zeroes the attention job counter.
// ---------------------------------------------------------------------------
#define NWA (2304 * 768)
#define NWP (768 * 768)
#define NWTOT ((NWA + NWP) / 4)

__global__ __launch_bounds__(256) void convert_w(
    const float* __restrict__ wa, const float* __restrict__ wp,
    u16* __restrict__ wab, u16* __restrict__ wpb, int* __restrict__ counter)
{
    if (blockIdx.x == 0 && threadIdx.x == 0) *counter = 0;
    for (int i4 = blockIdx.x * 256 + threadIdx.x; i4 < NWTOT; i4 += gridDim.x * 256) {
        int i = i4 * 4;
        const float* src; u16* dst; int off;
        if (i < NWA) { src = wa; dst = wab; off = i; }
        else         { src = wp; dst = wpb; off = i - NWA; }
        float4 v = *(const float4*)&src[off];
        ushort4 o;
        o.x = f2bf(v.x); o.y = f2bf(v.y); o.z = f2bf(v.z); o.w = f2bf(v.w);
        *(ushort4*)&dst[off] = o;
    }
}

// ---------------------------------------------------------------------------
// QKV GEMM: A = x (fp32, converted to bf16 during staging), W bf16.
// 128x128 tile, BK=32, 4 waves. Scatter epilogue -> q (x1/8), k, vT.
// ---------------------------------------------------------------------------
__global__ __launch_bounds__(256) void gemm_qkv(
    const float* __restrict__ A, const u16* __restrict__ Wt,
    u16* __restrict__ qb, u16* __restrict__ kb, u16* __restrict__ vtb)
{
    __shared__ __align__(16) u16 As[128][40];
    __shared__ __align__(16) u16 Bs[128][40];

    const int tid = threadIdx.x;
    const int bm = blockIdx.y * 128, bn = blockIdx.x * 128;
    const int w = tid >> 6, l = tid & 63;
    const int wr = (w >> 1) * 64, wc = (w & 1) * 64;
    const int lrow = l & 15, lg = l >> 4;

    const int srow = tid >> 2;
    const int scol = (tid & 3) * 8;

    f32x4 acc[4][4];
    const f32x4 zero4 = {0.f, 0.f, 0.f, 0.f};
#pragma unroll
    for (int mi = 0; mi < 4; ++mi)
#pragma unroll
        for (int ni = 0; ni < 4; ++ni) acc[mi][ni] = zero4;

    float4 ra0a = *(const float4*)&A[(size_t)(bm + srow)      * KDIM + scol];
    float4 ra0b = *(const float4*)&A[(size_t)(bm + srow)      * KDIM + scol + 4];
    float4 ra1a = *(const float4*)&A[(size_t)(bm + 64 + srow) * KDIM + scol];
    float4 ra1b = *(const float4*)&A[(size_t)(bm + 64 + srow) * KDIM + scol + 4];
    uint4  rb0  = *(const uint4*)&Wt[(size_t)(bn + srow)      * KDIM + scol];
    uint4  rb1  = *(const uint4*)&Wt[(size_t)(bn + 64 + srow) * KDIM + scol];

    for (int k0 = 0; k0 < KDIM; k0 += 32) {
        __syncthreads();
        *(uint4*)&As[srow][scol]      = pack8(ra0a, ra0b);
        *(uint4*)&As[64 + srow][scol] = pack8(ra1a, ra1b);
        *(uint4*)&Bs[srow][scol]      = rb0;
        *(uint4*)&Bs[64 + srow][scol] = rb1;
        __syncthreads();

        if (k0 + 32 < KDIM) {
            ra0a = *(const float4*)&A[(size_t)(bm + srow)      * KDIM + k0 + 32 + scol];
            ra0b = *(const float4*)&A[(size_t)(bm + srow)      * KDIM + k0 + 36 + scol];
            ra1a = *(const float4*)&A[(size_t)(bm + 64 + srow) * KDIM + k0 + 32 + scol];
            ra1b = *(const float4*)&A[(size_t)(bm + 64 + srow) * KDIM + k0 + 36 + scol];
            rb0  = *(const uint4*)&Wt[(size_t)(bn + srow)      * KDIM + k0 + 32 + scol];
            rb1  = *(const uint4*)&Wt[(size_t)(bn + 64 + srow) * KDIM + k0 + 32 + scol];
        }

        short8 af[4], bf[4];
#pragma unroll
        for (int mi = 0; mi < 4; ++mi)
            af[mi] = *(const short8*)&As[wr + mi * 16 + lrow][lg * 8];
#pragma unroll
        for (int ni = 0; ni < 4; ++ni)
            bf[ni] = *(const short8*)&Bs[wc + ni * 16 + lrow][lg * 8];
#pragma unroll
        for (int mi = 0; mi < 4; ++mi)
#pragma unroll
            for (int ni = 0; ni < 4; ++ni)
                acc[mi][ni] = __builtin_amdgcn_mfma_f32_16x16x32_bf16(
                    af[mi], bf[ni], acc[mi][ni], 0, 0, 0);
    }

#pragma unroll
    for (int ni = 0; ni < 4; ++ni) {
        const int colbase = bn + wc + ni * 16;
        const int which = colbase / C_DIM;
        const int h = (colbase % C_DIM) / HD;
        const int d = (colbase % HD) + lrow;
        const float qs = (which == 0) ? 0.125f : 1.0f;  // fold 1/sqrt(64) into Q
#pragma unroll
        for (int mi = 0; mi < 4; ++mi) {
            const int t0 = bm + wr + mi * 16 + lg * 4;
            const int bb2 = t0 >> 11, tt = t0 & 2047;
            const size_t bhoff = (size_t)(bb2 * NH + h);
            if (which == 2) {
                ushort4 pv;
                pv.x = f2bf(acc[mi][ni][0]); pv.y = f2bf(acc[mi][ni][1]);
                pv.z = f2bf(acc[mi][ni][2]); pv.w = f2bf(acc[mi][ni][3]);
                *(ushort4*)&vtb[(bhoff * HD + d) * T_DIM + tt] = pv;
            } else {
                u16* dst = (which == 0) ? qb : kb;
#pragma unroll
                for (int jj = 0; jj < 4; ++jj)
                    dst[(bhoff * T_DIM + tt + jj) * HD + d] = f2bf(acc[mi][ni][jj] * qs);
            }
        }
    }
}

// ---------------------------------------------------------------------------
// Output projection GEMM: A = attn output (bf16), W_proj bf16, out fp32.
// 64x128 tile (grid 6x64 = 384 blocks for CU coverage), BK=32, 4 waves
// arranged 2x2 over (rows 0/32, cols 0/64), wave tile 32x64, acc[2][4].
// ---------------------------------------------------------------------------
__global__ __launch_bounds__(256) void gemm_proj(
    const u16* __restrict__ A, const u16* __restrict__ Wt,
    float* __restrict__ dense)
{
    __shared__ __align__(16) u16 As[64][40];
    __shared__ __align__(16) u16 Bs[128][40];

    const int tid = threadIdx.x;
    const int bm = blockIdx.y * 64, bn = blockIdx.x * 128;
    const int w = tid >> 6, l = tid & 63;
    const int wr = (w >> 1) * 32, wc = (w & 1) * 64;
    const int lrow = l & 15, lg = l >> 4;

    const int srow = tid >> 2;          // 0..63
    const int scol = (tid & 3) * 8;

    f32x4 acc[2][4];
    const f32x4 zero4 = {0.f, 0.f, 0.f, 0.f};
#pragma unroll
    for (int mi = 0; mi < 2; ++mi)
#pragma unroll
        for (int ni = 0; ni < 4; ++ni) acc[mi][ni] = zero4;

    uint4 ra0 = *(const uint4*)&A [(size_t)(bm + srow)      * KDIM + scol];
    uint4 rb0 = *(const uint4*)&Wt[(size_t)(bn + srow)      * KDIM + scol];
    uint4 rb1 = *(const uint4*)&Wt[(size_t)(bn + 64 + srow) * KDIM + scol];

    for (int k0 = 0; k0 < KDIM; k0 += 32) {
        __syncthreads();
        *(uint4*)&As[srow][scol]      = ra0;
        *(uint4*)&Bs[srow][scol]      = rb0;
        *(uint4*)&Bs[64 + srow][scol] = rb1;
        __syncthreads();

        if (k0 + 32 < KDIM) {
            ra0 = *(const uint4*)&A [(size_t)(bm + srow)      * KDIM + k0 + 32 + scol];
            rb0 = *(const uint4*)&Wt[(size_t)(bn + srow)      * KDIM + k0 + 32 + scol];
            rb1 = *(const uint4*)&Wt[(size_t)(bn + 64 + srow) * KDIM + k0 + 32 + scol];
        }

        short8 af[2], bf[4];
#pragma unroll
        for (int mi = 0; mi < 2; ++mi)
            af[mi] = *(const short8*)&As[wr + mi * 16 + lrow][lg * 8];
#pragma unroll
        for (int ni = 0; ni < 4; ++ni)
            bf[ni] = *(const short8*)&Bs[wc + ni * 16 + lrow][lg * 8];
#pragma unroll
        for (int mi = 0; mi < 2; ++mi)
#pragma unroll
            for (int ni = 0; ni < 4; ++ni)
                acc[mi][ni] = __builtin_amdgcn_mfma_f32_16x16x32_bf16(
                    af[mi], bf[ni], acc[mi][ni], 0, 0, 0);
    }

#pragma unroll
    for (int ni = 0; ni < 4; ++ni) {
        const int col = bn + wc + ni * 16 + lrow;
#pragma unroll
        for (int mi = 0; mi < 2; ++mi) {
            const int m0 = bm + wr + mi * 16 + lg * 4;
#pragma unroll
            for (int jj = 0; jj < 4; ++jj)
                dense[(size_t)(m0 + jj) * C_DIM + col] = acc[mi][ni][jj];
        }
    }
}

// ---------------------------------------------------------------------------
// Flash attention, swapped-QK^T bf16 MFMA. 8-wave (512 thr) persistent blocks.
// Wave pairs split the key range: group g = w>>2 handles 64-key sub-blocks
// with index ksub = 2*kt+g; private (m,l,o) merged at job end via LDS (exact
// LSE merge). Halves the per-job dependent chain; 16 waves/CU occupancy.
// ---------------------------------------------------------------------------
__global__ __launch_bounds__(512, 2) void attn_mfma(
    const u16* __restrict__ q, const u16* __restrict__ k,
    const u16* __restrict__ vt, u16* __restrict__ aw, int* __restrict__ counter)
{
    // pool: Ks[128][68] (17408 B) | Vts[64][132] (16896 B) | Ps[8][16][72] (18432 B)
    // merge overlay (job end, inside Ks footprint): bufo[4][64]x4 f32x4 (16384 B)
    //                                               bufm[4][16], bufl[4][16]
    __shared__ __align__(16) char pool[52736];
    __shared__ int job_s;
    u16 (*Ks)[68]      = (u16 (*)[68])  pool;
    u16 (*Vts)[132]    = (u16 (*)[132])(pool + 17408);
    u16 (*Ps)[16][72]  = (u16 (*)[16][72])(pool + 34304);
    f32x4* bufo        = (f32x4*)pool;
    float* bufm        = (float*)(pool + 16384);
    float* bufl        = (float*)(pool + 16384 + 256);

    const int tid = threadIdx.x;
    const int w = tid >> 6, l = tid & 63;
    const int g = w >> 2, wq = w & 3;
    const int lrow = l & 15, lg = l >> 4;
    const f32x4 zero4 = {0.f, 0.f, 0.f, 0.f};

    const int krow = tid >> 2, kcol = (tid & 3) * 16;   // K stage: [128][64]
    const int vrow = tid >> 3, vcol = (tid & 7) * 16;   // V^T stage: [64][128]

    for (;;) {
        __syncthreads();                     // prior job's LDS reads done
        if (tid == 0) job_s = atomicAdd(counter, 1);
        __syncthreads();
        const int j = job_s;
        if (j >= NJOBS) break;

        const int qt = 31 - (j / 24);        // big q-tiles first (LPT)
        const int bh = j - (j / 24) * 24;
        const int bb = bh / NH, hh = bh % NH;
        const int qbase = qt * 64 + wq * 16;
        const int qg = qbase + lrow;

        const u16* Qp = q  + (size_t)bh * T_DIM * HD;
        const u16* Kp = k  + (size_t)bh * T_DIM * HD;
        const u16* Vp = vt + (size_t)bh * HD * T_DIM;

        const short8 aq0 = *(const short8*)&Qp[(size_t)(qbase + lrow) * HD + lg * 8];
        const short8 aq1 = *(const short8*)&Qp[(size_t)(qbase + lrow) * HD + 32 + lg * 8];

        f32x4 o[4];
#pragma unroll
        for (int n = 0; n < 4; ++n) o[n] = zero4;
        float m_run = -3.0e38f;
        float l_run = 0.0f;

        const int nkt = qt / 2 + 1;          // 128-key staging rounds
        for (int kt = 0; kt < nkt; ++kt) {
            const int kk0 = kt * 128;
            __syncthreads();                 // prior tile's LDS reads complete

            {   // stage K (128x64) + V^T (64x128); transient regs
                uint4 kra = *(const uint4*)&Kp[(size_t)(kk0 + krow) * HD + kcol];
                uint4 krb = *(const uint4*)&Kp[(size_t)(kk0 + krow) * HD + kcol + 8];
                uint4 vra = *(const uint4*)&Vp[(size_t)vrow * T_DIM + kk0 + vcol];
                uint4 vrb = *(const uint4*)&Vp[(size_t)vrow * T_DIM + kk0 + vcol + 8];
                *(uint4*)&Ks[krow][kcol]      = kra;
                *(uint4*)&Ks[krow][kcol + 8]  = krb;
                *(uint4*)&Vts[vrow][vcol]     = vra;
                *(uint4*)&Vts[vrow][vcol + 8] = vrb;
            }
            __syncthreads();

            const int ksub = 2 * kt + g;     // this group's 64-key sub-block
            if (ksub <= qt) {
                const int kb0 = g * 64;      // local base in Ks rows / Vts cols

                // ---- S^T: s[n][jj] = S[k=ksub*64+n*16+lg*4+jj][q=qg]
                f32x4 s[4];
                __builtin_amdgcn_s_setprio(1);
#pragma unroll
                for (int n = 0; n < 4; ++n) {
                    const short8 kf0 = *(const short8*)&Ks[kb0 + n * 16 + lrow][lg * 8];
                    const short8 kf1 = *(const short8*)&Ks[kb0 + n * 16 + lrow][32 + lg * 8];
                    s[n] = __builtin_amdgcn_mfma_f32_16x16x32_bf16(kf0, aq0, zero4, 0, 0, 0);
                    s[n] = __builtin_amdgcn_mfma_f32_16x16x32_bf16(kf1, aq1, s[n], 0, 0, 0);
                }
                __builtin_amdgcn_s_setprio(0);

                if (ksub == qt) {            // diagonal sub-block: causal mask
#pragma unroll
                    for (int n = 0; n < 4; ++n)
#pragma unroll
                        for (int jj = 0; jj < 4; ++jj)
                            if (ksub * 64 + n * 16 + lg * 4 + jj > qg)
                                s[n][jj] = -3.0e38f;
                }

                // ---- online softmax (per-lane tree + 2 shuffles)
                f32x4 t2 = max4(max4(s[0], s[1]), max4(s[2], s[3]));
                float rm = fmaxf(fmaxf(t2[0], t2[1]), fmaxf(t2[2], t2[3]));
                rm = fmaxf(rm, __shfl_xor(rm, 16));
                rm = fmaxf(rm, __shfl_xor(rm, 32));

                const bool grow = !__all(rm <= m_run);   // defer-rescale (exact)
                float m_new = m_run, alpha = 1.0f;
                if (grow) {
                    m_new = fmaxf(m_run, rm);
                    alpha = __expf(m_run - m_new);
                    m_run = m_new;
                }

#pragma unroll
                for (int n = 0; n < 4; ++n)
#pragma unroll
                    for (int jj = 0; jj < 4; ++jj)
                        s[n][jj] = __expf(s[n][jj] - m_new);

                f32x4 a2 = (s[0] + s[1]) + (s[2] + s[3]);
                float rs = (a2[0] + a2[1]) + (a2[2] + a2[3]);
                rs += __shfl_xor(rs, 16);
                rs += __shfl_xor(rs, 32);
                l_run = l_run * alpha + rs;

                // ---- P -> LDS bf16 (k lane-local)
#pragma unroll
                for (int n = 0; n < 4; ++n) {
                    uint2 pr;
                    pr.x = cvtpk(s[n][0], s[n][1]);
                    pr.y = cvtpk(s[n][2], s[n][3]);
                    *(uint2*)&Ps[w][lrow][n * 16 + lg * 4] = pr;
                }

                if (grow) {
#pragma unroll
                    for (int jj = 0; jj < 4; ++jj) {
                        const float aj = __shfl(alpha, lg * 4 + jj);
                        o[0][jj] *= aj; o[1][jj] *= aj;
                        o[2][jj] *= aj; o[3][jj] *= aj;
                    }
                }

                // ---- O += P V (same-wave LDS write->read order)
                const short8 ap0 = *(const short8*)&Ps[w][lrow][lg * 8];
                const short8 ap1 = *(const short8*)&Ps[w][lrow][32 + lg * 8];
                __builtin_amdgcn_s_setprio(1);
#pragma unroll
                for (int n = 0; n < 4; ++n) {
                    const short8 bv0 = *(const short8*)&Vts[n * 16 + lrow][kb0 + lg * 8];
                    const short8 bv1 = *(const short8*)&Vts[n * 16 + lrow][kb0 + 32 + lg * 8];
                    o[n] = __builtin_amdgcn_mfma_f32_16x16x32_bf16(ap0, bv0, o[n], 0, 0, 0);
                    o[n] = __builtin_amdgcn_mfma_f32_16x16x32_bf16(ap1, bv1, o[n], 0, 0, 0);
                }
                __builtin_amdgcn_s_setprio(0);
            }
        }

        // ---- merge wave pairs (g=1 -> LDS, g=0 merges + writes out)
        __syncthreads();                     // all compute done; Ks reusable
        if (g == 1) {
#pragma unroll
            for (int n = 0; n < 4; ++n) bufo[(wq * 64 + l) * 4 + n] = o[n];
            if (l < 16) { bufm[wq * 16 + l] = m_run; bufl[wq * 16 + l] = l_run; }
        }
        __syncthreads();
        if (g == 0) {
            f32x4 o1[4];
#pragma unroll
            for (int n = 0; n < 4; ++n) o1[n] = bufo[(wq * 64 + l) * 4 + n];
#pragma unroll
            for (int jj = 0; jj < 4; ++jj) {
                const int qrow = lg * 4 + jj;
                const float m0j = __shfl(m_run, qrow);
                const float l0j = __shfl(l_run, qrow);
                const float m1j = bufm[wq * 16 + qrow];
                const float l1j = bufl[wq * 16 + qrow];
                const float mf = fmaxf(m0j, m1j);
                const float a0 = __expf(m0j - mf);
                const float a1 = __expf(m1j - mf);
                const float inv = 1.0f / (l0j * a0 + l1j * a1);
                const size_t m = (size_t)bb * T_DIM + qbase + qrow;
#pragma unroll
                for (int n = 0; n < 4; ++n)
                    aw[m * C_DIM + hh * HD + n * 16 + lrow] =
                        f2bf((o[n][jj] * a0 + o1[n][jj] * a1) * inv);
            }
        }
    }
}

// ---------------------------------------------------------------------------
extern "C" void kernel_launch(void* const* d_in, const int* in_sizes, int n_in,
                              void* d_out, int out_size, void* d_ws, size_t ws_size,
                              hipStream_t stream) {
    const float* x      = (const float*)d_in[0];
    const float* W_attn = (const float*)d_in[1];
    const float* W_proj = (const float*)d_in[2];
    float* out = (float*)d_out;

    char* ws = (char*)d_ws;
    u16* wab = (u16*)ws;                       ws += (size_t)NWA * 2;
    u16* wpb = (u16*)ws;                       ws += (size_t)NWP * 2;
    u16* qb  = (u16*)ws;                       ws += (size_t)24 * T_DIM * HD * 2;
    u16* kb  = (u16*)ws;                       ws += (size_t)24 * T_DIM * HD * 2;
    u16* vtb = (u16*)ws;                       ws += (size_t)24 * T_DIM * HD * 2;
    u16* awb = (u16*)ws;                       ws += (size_t)4096 * C_DIM * 2;
    int* cnt = (int*)ws;

    convert_w<<<512, 256, 0, stream>>>(W_attn, W_proj, wab, wpb, cnt);

    gemm_qkv<<<dim3(2304 / 128, 4096 / 128), 256, 0, stream>>>(
        x, wab, qb, kb, vtb);

    attn_mfma<<<512, 512, 0, stream>>>(qb, kb, vtb, awb, cnt);

    gemm_proj<<<dim3(768 / 128, 4096 / 64), 256, 0, stream>>>(
        awb, wpb, out);
}

// Round 7
// 116.749 us; speedup vs baseline: 1.7284x; 1.7284x over previous
//
#include <hip/hip_runtime.h>

#define T_DIM 2048
#define C_DIM 768
#define NH    12
#define HD    64
#define KDIM  768
#define NJOBS (24 * 32)

typedef __attribute__((ext_vector_type(8))) short short8;
typedef __attribute__((ext_vector_type(4))) float f32x4;
typedef unsigned short u16;

__device__ __forceinline__ u16 f2bf(float f) {
    unsigned int u = __builtin_bit_cast(unsigned int, f);
    u = (u + 0x7fffu + ((u >> 16) & 1u)) >> 16;   // RNE
    return (u16)u;
}
__device__ __forceinline__ f32x4 max4(f32x4 a, f32x4 b) {
    f32x4 r; r[0]=fmaxf(a[0],b[0]); r[1]=fmaxf(a[1],b[1]);
    r[2]=fmaxf(a[2],b[2]); r[3]=fmaxf(a[3],b[3]); return r;
}
__device__ __forceinline__ unsigned int cvtpk(float a, float b) {
    unsigned int r;
    asm("v_cvt_pk_bf16_f32 %0, %1, %2" : "=v"(r) : "v"(a), "v"(b));
    return r;
}
__device__ __forceinline__ uint4 pack8(float4 a, float4 b) {
    return make_uint4(cvtpk(a.x, a.y), cvtpk(a.z, a.w),
                      cvtpk(b.x, b.y), cvtpk(b.z, b.w));
}

// ---------------------------------------------------------------------------
// fp32 -> bf16 conversion of W_attn, W_proj only (x folded into gemm_qkv).
// Also zeroes the attention job counter.
// ---------------------------------------------------------------------------
#define NWA (2304 * 768)
#define NWP (768 * 768)
#define NWTOT ((NWA + NWP) / 4)

__global__ __launch_bounds__(256) void convert_w(
    const float* __restrict__ wa, const float* __restrict__ wp,
    u16* __restrict__ wab, u16* __restrict__ wpb, int* __restrict__ counter)
{
    if (blockIdx.x == 0 && threadIdx.x == 0) *counter = 0;
    for (int i4 = blockIdx.x * 256 + threadIdx.x; i4 < NWTOT; i4 += gridDim.x * 256) {
        int i = i4 * 4;
        const float* src; u16* dst; int off;
        if (i < NWA) { src = wa; dst = wab; off = i; }
        else         { src = wp; dst = wpb; off = i - NWA; }
        float4 v = *(const float4*)&src[off];
        ushort4 o;
        o.x = f2bf(v.x); o.y = f2bf(v.y); o.z = f2bf(v.z); o.w = f2bf(v.w);
        *(ushort4*)&dst[off] = o;
    }
}

// ---------------------------------------------------------------------------
// QKV GEMM: A = x (fp32, converted to bf16 during staging), W bf16.
// 128x128 tile, BK=32, 4 waves. Scatter epilogue -> q (x1/8), k, vT.
// ---------------------------------------------------------------------------
__global__ __launch_bounds__(256) void gemm_qkv(
    const float* __restrict__ A, const u16* __restrict__ Wt,
    u16* __restrict__ qb, u16* __restrict__ kb, u16* __restrict__ vtb)
{
    __shared__ __align__(16) u16 As[128][40];
    __shared__ __align__(16) u16 Bs[128][40];

    const int tid = threadIdx.x;
    const int bm = blockIdx.y * 128, bn = blockIdx.x * 128;
    const int w = tid >> 6, l = tid & 63;
    const int wr = (w >> 1) * 64, wc = (w & 1) * 64;
    const int lrow = l & 15, lg = l >> 4;

    const int srow = tid >> 2;
    const int scol = (tid & 3) * 8;

    f32x4 acc[4][4];
    const f32x4 zero4 = {0.f, 0.f, 0.f, 0.f};
#pragma unroll
    for (int mi = 0; mi < 4; ++mi)
#pragma unroll
        for (int ni = 0; ni < 4; ++ni) acc[mi][ni] = zero4;

    float4 ra0a = *(const float4*)&A[(size_t)(bm + srow)      * KDIM + scol];
    float4 ra0b = *(const float4*)&A[(size_t)(bm + srow)      * KDIM + scol + 4];
    float4 ra1a = *(const float4*)&A[(size_t)(bm + 64 + srow) * KDIM + scol];
    float4 ra1b = *(const float4*)&A[(size_t)(bm + 64 + srow) * KDIM + scol + 4];
    uint4  rb0  = *(const uint4*)&Wt[(size_t)(bn + srow)      * KDIM + scol];
    uint4  rb1  = *(const uint4*)&Wt[(size_t)(bn + 64 + srow) * KDIM + scol];

    for (int k0 = 0; k0 < KDIM; k0 += 32) {
        __syncthreads();
        *(uint4*)&As[srow][scol]      = pack8(ra0a, ra0b);
        *(uint4*)&As[64 + srow][scol] = pack8(ra1a, ra1b);
        *(uint4*)&Bs[srow][scol]      = rb0;
        *(uint4*)&Bs[64 + srow][scol] = rb1;
        __syncthreads();

        if (k0 + 32 < KDIM) {
            ra0a = *(const float4*)&A[(size_t)(bm + srow)      * KDIM + k0 + 32 + scol];
            ra0b = *(const float4*)&A[(size_t)(bm + srow)      * KDIM + k0 + 36 + scol];
            ra1a = *(const float4*)&A[(size_t)(bm + 64 + srow) * KDIM + k0 + 32 + scol];
            ra1b = *(const float4*)&A[(size_t)(bm + 64 + srow) * KDIM + k0 + 36 + scol];
            rb0  = *(const uint4*)&Wt[(size_t)(bn + srow)      * KDIM + k0 + 32 + scol];
            rb1  = *(const uint4*)&Wt[(size_t)(bn + 64 + srow) * KDIM + k0 + 32 + scol];
        }

        short8 af[4], bf[4];
#pragma unroll
        for (int mi = 0; mi < 4; ++mi)
            af[mi] = *(const short8*)&As[wr + mi * 16 + lrow][lg * 8];
#pragma unroll
        for (int ni = 0; ni < 4; ++ni)
            bf[ni] = *(const short8*)&Bs[wc + ni * 16 + lrow][lg * 8];
#pragma unroll
        for (int mi = 0; mi < 4; ++mi)
#pragma unroll
            for (int ni = 0; ni < 4; ++ni)
                acc[mi][ni] = __builtin_amdgcn_mfma_f32_16x16x32_bf16(
                    af[mi], bf[ni], acc[mi][ni], 0, 0, 0);
    }

#pragma unroll
    for (int ni = 0; ni < 4; ++ni) {
        const int colbase = bn + wc + ni * 16;
        const int which = colbase / C_DIM;
        const int h = (colbase % C_DIM) / HD;
        const int d = (colbase % HD) + lrow;
        const float qs = (which == 0) ? 0.125f : 1.0f;  // fold 1/sqrt(64) into Q
#pragma unroll
        for (int mi = 0; mi < 4; ++mi) {
            const int t0 = bm + wr + mi * 16 + lg * 4;
            const int bb2 = t0 >> 11, tt = t0 & 2047;
            const size_t bhoff = (size_t)(bb2 * NH + h);
            if (which == 2) {
                ushort4 pv;
                pv.x = f2bf(acc[mi][ni][0]); pv.y = f2bf(acc[mi][ni][1]);
                pv.z = f2bf(acc[mi][ni][2]); pv.w = f2bf(acc[mi][ni][3]);
                *(ushort4*)&vtb[(bhoff * HD + d) * T_DIM + tt] = pv;
            } else {
                u16* dst = (which == 0) ? qb : kb;
#pragma unroll
                for (int jj = 0; jj < 4; ++jj)
                    dst[(bhoff * T_DIM + tt + jj) * HD + d] = f2bf(acc[mi][ni][jj] * qs);
            }
        }
    }
}

// ---------------------------------------------------------------------------
// Output projection GEMM: A = attn output (bf16), W_proj bf16, out fp32.
// 64x128 tile (grid 6x64 = 384 blocks), BK=32, 4 waves 2x2, wave tile 32x64.
// ---------------------------------------------------------------------------
__global__ __launch_bounds__(256) void gemm_proj(
    const u16* __restrict__ A, const u16* __restrict__ Wt,
    float* __restrict__ dense)
{
    __shared__ __align__(16) u16 As[64][40];
    __shared__ __align__(16) u16 Bs[128][40];

    const int tid = threadIdx.x;
    const int bm = blockIdx.y * 64, bn = blockIdx.x * 128;
    const int w = tid >> 6, l = tid & 63;
    const int wr = (w >> 1) * 32, wc = (w & 1) * 64;
    const int lrow = l & 15, lg = l >> 4;

    const int srow = tid >> 2;          // 0..63
    const int scol = (tid & 3) * 8;

    f32x4 acc[2][4];
    const f32x4 zero4 = {0.f, 0.f, 0.f, 0.f};
#pragma unroll
    for (int mi = 0; mi < 2; ++mi)
#pragma unroll
        for (int ni = 0; ni < 4; ++ni) acc[mi][ni] = zero4;

    uint4 ra0 = *(const uint4*)&A [(size_t)(bm + srow)      * KDIM + scol];
    uint4 rb0 = *(const uint4*)&Wt[(size_t)(bn + srow)      * KDIM + scol];
    uint4 rb1 = *(const uint4*)&Wt[(size_t)(bn + 64 + srow) * KDIM + scol];

    for (int k0 = 0; k0 < KDIM; k0 += 32) {
        __syncthreads();
        *(uint4*)&As[srow][scol]      = ra0;
        *(uint4*)&Bs[srow][scol]      = rb0;
        *(uint4*)&Bs[64 + srow][scol] = rb1;
        __syncthreads();

        if (k0 + 32 < KDIM) {
            ra0 = *(const uint4*)&A [(size_t)(bm + srow)      * KDIM + k0 + 32 + scol];
            rb0 = *(const uint4*)&Wt[(size_t)(bn + srow)      * KDIM + k0 + 32 + scol];
            rb1 = *(const uint4*)&Wt[(size_t)(bn + 64 + srow) * KDIM + k0 + 32 + scol];
        }

        short8 af[2], bf[4];
#pragma unroll
        for (int mi = 0; mi < 2; ++mi)
            af[mi] = *(const short8*)&As[wr + mi * 16 + lrow][lg * 8];
#pragma unroll
        for (int ni = 0; ni < 4; ++ni)
            bf[ni] = *(const short8*)&Bs[wc + ni * 16 + lrow][lg * 8];
#pragma unroll
        for (int mi = 0; mi < 2; ++mi)
#pragma unroll
            for (int ni = 0; ni < 4; ++ni)
                acc[mi][ni] = __builtin_amdgcn_mfma_f32_16x16x32_bf16(
                    af[mi], bf[ni], acc[mi][ni], 0, 0, 0);
    }

#pragma unroll
    for (int ni = 0; ni < 4; ++ni) {
        const int col = bn + wc + ni * 16 + lrow;
#pragma unroll
        for (int mi = 0; mi < 2; ++mi) {
            const int m0 = bm + wr + mi * 16 + lg * 4;
#pragma unroll
            for (int jj = 0; jj < 4; ++jj)
                dense[(size_t)(m0 + jj) * C_DIM + col] = acc[mi][ni][jj];
        }
    }
}

// ---------------------------------------------------------------------------
// Flash attention, swapped-QK^T bf16 MFMA — R5 structure (4 waves, 256 thr,
// two sequential 64-key sub-blocks per 128-key staging round: sub0's PV
// overlaps sub1's QK in the wave's instruction stream — key ILP source).
// Grid 768 persistent blocks -> 3 blocks/CU resident (R5 used 512 -> 2/CU).
// ---------------------------------------------------------------------------
__global__ __launch_bounds__(256, 2) void attn_mfma(
    const u16* __restrict__ q, const u16* __restrict__ k,
    const u16* __restrict__ vt, u16* __restrict__ aw, int* __restrict__ counter)
{
    __shared__ __align__(16) u16 Ks [128][72];    // K[t_local][d]
    __shared__ __align__(16) u16 Vts[64][136];    // V^T[d][t_local]
    __shared__ __align__(16) u16 Ps [4][16][72];  // per-wave P[q_local][k_local(64)]
    __shared__ int job_s;

    const int tid = threadIdx.x, w = tid >> 6, l = tid & 63;
    const int lrow = l & 15, lg = l >> 4;
    const f32x4 zero4 = {0.f, 0.f, 0.f, 0.f};

    for (;;) {
        __syncthreads();                       // all waves done with prior job's LDS
        if (tid == 0) job_s = atomicAdd(counter, 1);
        __syncthreads();
        const int j = job_s;
        if (j >= NJOBS) break;                 // uniform exit

        const int qt = 31 - (j / 24);          // big q-tiles first (LPT)
        const int bh = j - (j / 24) * 24;
        const int bb = bh / NH, hh = bh % NH;
        const int qbase = qt * 64 + w * 16;
        const int qg = qbase + lrow;           // this lane's q row

        const u16* Qp = q  + (size_t)bh * T_DIM * HD;
        const u16* Kp = k  + (size_t)bh * T_DIM * HD;
        const u16* Vp = vt + (size_t)bh * HD * T_DIM;

        const short8 aq0 = *(const short8*)&Qp[(size_t)(qbase + lrow) * HD + lg * 8];
        const short8 aq1 = *(const short8*)&Qp[(size_t)(qbase + lrow) * HD + 32 + lg * 8];

        f32x4 o[4];
#pragma unroll
        for (int n = 0; n < 4; ++n) o[n] = zero4;
        float m_run = -3.0e38f;
        float l_run = 0.0f;

        const int nkt = qt / 2 + 1;
        for (int kt = 0; kt < nkt; ++kt) {
            const int kk0 = kt * 128;
            __syncthreads();                   // prior tile's LDS reads complete

            // ---- stage K (128x64) and V^T (64x128); transient regs only
            {
                uint4 kr[4], vr[4];
#pragma unroll
                for (int t = 0; t < 4; ++t) {
                    kr[t] = *(const uint4*)&Kp[(size_t)(kk0 + t * 32 + (tid >> 3)) * HD + (tid & 7) * 8];
                    vr[t] = *(const uint4*)&Vp[(size_t)(t * 16 + (tid >> 4)) * T_DIM + kk0 + (tid & 15) * 8];
                }
#pragma unroll
                for (int t = 0; t < 4; ++t) {
                    *(uint4*)&Ks [t * 32 + (tid >> 3)][(tid & 7) * 8]  = kr[t];
                    *(uint4*)&Vts[t * 16 + (tid >> 4)][(tid & 15) * 8] = vr[t];
                }
            }
            __syncthreads();

            const bool last = (kt == nkt - 1);
            const int nsub = (last && (qt & 1) == 0) ? 1 : 2;  // skip fully-masked half
            for (int sub = 0; sub < nsub; ++sub) {
                const int kb0 = kk0 + sub * 64;
                const bool masked = last && (sub == nsub - 1);

                // ---- S^T sub-tile: s[n][jj] = S[k=kb0+n*16+lg*4+jj][q=qg]
                f32x4 s[4];
#pragma unroll
                for (int n = 0; n < 4; ++n) {
                    const short8 kf0 = *(const short8*)&Ks[sub * 64 + n * 16 + lrow][lg * 8];
                    const short8 kf1 = *(const short8*)&Ks[sub * 64 + n * 16 + lrow][32 + lg * 8];
                    s[n] = __builtin_amdgcn_mfma_f32_16x16x32_bf16(kf0, aq0, zero4, 0, 0, 0);
                    s[n] = __builtin_amdgcn_mfma_f32_16x16x32_bf16(kf1, aq1, s[n], 0, 0, 0);
                }

                if (masked) {
#pragma unroll
                    for (int n = 0; n < 4; ++n)
#pragma unroll
                        for (int jj = 0; jj < 4; ++jj)
                            if (kb0 + n * 16 + lg * 4 + jj > qg) s[n][jj] = -3.0e38f;
                }

                // ---- online softmax (per-lane tree + 2 shuffles)
                f32x4 t2 = max4(max4(s[0], s[1]), max4(s[2], s[3]));
                float rm = fmaxf(fmaxf(t2[0], t2[1]), fmaxf(t2[2], t2[3]));
                rm = fmaxf(rm, __shfl_xor(rm, 16));
                rm = fmaxf(rm, __shfl_xor(rm, 32));
                const float m_new = fmaxf(m_run, rm);
                const float alpha = __expf(m_run - m_new);
                m_run = m_new;

#pragma unroll
                for (int n = 0; n < 4; ++n)
#pragma unroll
                    for (int jj = 0; jj < 4; ++jj)
                        s[n][jj] = __expf(s[n][jj] - m_new);

                f32x4 a2 = (s[0] + s[1]) + (s[2] + s[3]);
                float rs = (a2[0] + a2[1]) + (a2[2] + a2[3]);
                rs += __shfl_xor(rs, 16);
                rs += __shfl_xor(rs, 32);
                l_run = l_run * alpha + rs;

                // ---- P -> LDS bf16 (k lane-local: no shuffles)
#pragma unroll
                for (int n = 0; n < 4; ++n) {
                    uint2 pr;
                    pr.x = cvtpk(s[n][0], s[n][1]);
                    pr.y = cvtpk(s[n][2], s[n][3]);
                    *(uint2*)&Ps[w][lrow][n * 16 + lg * 4] = pr;
                }

                // ---- rescale O
#pragma unroll
                for (int jj = 0; jj < 4; ++jj) {
                    const float aj = __shfl(alpha, lg * 4 + jj);
                    o[0][jj] *= aj; o[1][jj] *= aj; o[2][jj] *= aj; o[3][jj] *= aj;
                }

                // ---- O += P V (same-wave LDS RW order guarantees Ps ready)
                const short8 ap0 = *(const short8*)&Ps[w][lrow][lg * 8];
                const short8 ap1 = *(const short8*)&Ps[w][lrow][32 + lg * 8];
#pragma unroll
                for (int n = 0; n < 4; ++n) {
                    const short8 bv0 = *(const short8*)&Vts[n * 16 + lrow][sub * 64 + lg * 8];
                    const short8 bv1 = *(const short8*)&Vts[n * 16 + lrow][sub * 64 + 32 + lg * 8];
                    o[n] = __builtin_amdgcn_mfma_f32_16x16x32_bf16(ap0, bv0, o[n], 0, 0, 0);
                    o[n] = __builtin_amdgcn_mfma_f32_16x16x32_bf16(ap1, bv1, o[n], 0, 0, 0);
                }
            }
        }

        // ---- epilogue: normalize, write bf16 [B*T, C]
#pragma unroll
        for (int jj = 0; jj < 4; ++jj) {
            const float lj = __shfl(l_run, lg * 4 + jj);
            const float inv = 1.0f / lj;
            const size_t m = (size_t)bb * T_DIM + qbase + lg * 4 + jj;
#pragma unroll
            for (int n = 0; n < 4; ++n)
                aw[m * C_DIM + hh * HD + n * 16 + lrow] = f2bf(o[n][jj] * inv);
        }
    }
}

// ---------------------------------------------------------------------------
extern "C" void kernel_launch(void* const* d_in, const int* in_sizes, int n_in,
                              void* d_out, int out_size, void* d_ws, size_t ws_size,
                              hipStream_t stream) {
    const float* x      = (const float*)d_in[0];
    const float* W_attn = (const float*)d_in[1];
    const float* W_proj = (const float*)d_in[2];
    float* out = (float*)d_out;

    char* ws = (char*)d_ws;
    u16* wab = (u16*)ws;                       ws += (size_t)NWA * 2;
    u16* wpb = (u16*)ws;                       ws += (size_t)NWP * 2;
    u16* qb  = (u16*)ws;                       ws += (size_t)24 * T_DIM * HD * 2;
    u16* kb  = (u16*)ws;                       ws += (size_t)24 * T_DIM * HD * 2;
    u16* vtb = (u16*)ws;                       ws += (size_t)24 * T_DIM * HD * 2;
    u16* awb = (u16*)ws;                       ws += (size_t)4096 * C_DIM * 2;
    int* cnt = (int*)ws;

    convert_w<<<512, 256, 0, stream>>>(W_attn, W_proj, wab, wpb, cnt);

    gemm_qkv<<<dim3(2304 / 128, 4096 / 128), 256, 0, stream>>>(
        x, wab, qb, kb, vtb);

    attn_mfma<<<768, 256, 0, stream>>>(qb, kb, vtb, awb, cnt);

    gemm_proj<<<dim3(768 / 128, 4096 / 64), 256, 0, stream>>>(
        awb, wpb, out);
}

// Round 8
// 107.690 us; speedup vs baseline: 1.8738x; 1.0841x over previous
//
#include <hip/hip_runtime.h>

#define T_DIM 2048
#define C_DIM 768
#define NH    12
#define HD    64
#define KDIM  768
#define NJOBS (24 * 32)

typedef __attribute__((ext_vector_type(8))) short short8;
typedef __attribute__((ext_vector_type(4))) float f32x4;
typedef unsigned short u16;

__device__ __forceinline__ u16 f2bf(float f) {
    unsigned int u = __builtin_bit_cast(unsigned int, f);
    u = (u + 0x7fffu + ((u >> 16) & 1u)) >> 16;   // RNE
    return (u16)u;
}
__device__ __forceinline__ f32x4 max4(f32x4 a, f32x4 b) {
    f32x4 r; r[0]=fmaxf(a[0],b[0]); r[1]=fmaxf(a[1],b[1]);
    r[2]=fmaxf(a[2],b[2]); r[3]=fmaxf(a[3],b[3]); return r;
}
__device__ __forceinline__ unsigned int cvtpk(float a, float b) {
    unsigned int r;
    asm("v_cvt_pk_bf16_f32 %0, %1, %2" : "=v"(r) : "v"(a), "v"(b));
    return r;
}
__device__ __forceinline__ uint4 pack8(float4 a, float4 b) {
    return make_uint4(cvtpk(a.x, a.y), cvtpk(a.z, a.w),
                      cvtpk(b.x, b.y), cvtpk(b.z, b.w));
}
// async global->LDS, 16B per lane; LDS dest = wave-uniform base + lane*16
__device__ __forceinline__ void gload16(const u16* g, u16* l) {
    __builtin_amdgcn_global_load_lds(
        (const __attribute__((address_space(1))) unsigned int*)g,
        (__attribute__((address_space(3))) unsigned int*)l, 16, 0, 0);
}

// ---------------------------------------------------------------------------
// fp32 -> bf16 conversion of W_attn, W_proj; zeroes the attn job counter.
// ---------------------------------------------------------------------------
#define NWA (2304 * 768)
#define NWP (768 * 768)
#define NWTOT ((NWA + NWP) / 4)

__global__ __launch_bounds__(256) void convert_w(
    const float* __restrict__ wa, const float* __restrict__ wp,
    u16* __restrict__ wab, u16* __restrict__ wpb, int* __restrict__ counter)
{
    if (blockIdx.x == 0 && threadIdx.x == 0) *counter = 0;
    for (int i4 = blockIdx.x * 256 + threadIdx.x; i4 < NWTOT; i4 += gridDim.x * 256) {
        int i = i4 * 4;
        const float* src; u16* dst; int off;
        if (i < NWA) { src = wa; dst = wab; off = i; }
        else         { src = wp; dst = wpb; off = i - NWA; }
        float4 v = *(const float4*)&src[off];
        ushort4 o;
        o.x = f2bf(v.x); o.y = f2bf(v.y); o.z = f2bf(v.z); o.w = f2bf(v.w);
        *(ushort4*)&dst[off] = o;
    }
}

// ---------------------------------------------------------------------------
// QKV GEMM: A = x (fp32 -> bf16 during staging), W bf16. 128x128, BK=32.
// ---------------------------------------------------------------------------
__global__ __launch_bounds__(256) void gemm_qkv(
    const float* __restrict__ A, const u16* __restrict__ Wt,
    u16* __restrict__ qb, u16* __restrict__ kb, u16* __restrict__ vtb)
{
    __shared__ __align__(16) u16 As[128][40];
    __shared__ __align__(16) u16 Bs[128][40];

    const int tid = threadIdx.x;
    const int bm = blockIdx.y * 128, bn = blockIdx.x * 128;
    const int w = tid >> 6, l = tid & 63;
    const int wr = (w >> 1) * 64, wc = (w & 1) * 64;
    const int lrow = l & 15, lg = l >> 4;

    const int srow = tid >> 2;
    const int scol = (tid & 3) * 8;

    f32x4 acc[4][4];
    const f32x4 zero4 = {0.f, 0.f, 0.f, 0.f};
#pragma unroll
    for (int mi = 0; mi < 4; ++mi)
#pragma unroll
        for (int ni = 0; ni < 4; ++ni) acc[mi][ni] = zero4;

    float4 ra0a = *(const float4*)&A[(size_t)(bm + srow)      * KDIM + scol];
    float4 ra0b = *(const float4*)&A[(size_t)(bm + srow)      * KDIM + scol + 4];
    float4 ra1a = *(const float4*)&A[(size_t)(bm + 64 + srow) * KDIM + scol];
    float4 ra1b = *(const float4*)&A[(size_t)(bm + 64 + srow) * KDIM + scol + 4];
    uint4  rb0  = *(const uint4*)&Wt[(size_t)(bn + srow)      * KDIM + scol];
    uint4  rb1  = *(const uint4*)&Wt[(size_t)(bn + 64 + srow) * KDIM + scol];

    for (int k0 = 0; k0 < KDIM; k0 += 32) {
        __syncthreads();
        *(uint4*)&As[srow][scol]      = pack8(ra0a, ra0b);
        *(uint4*)&As[64 + srow][scol] = pack8(ra1a, ra1b);
        *(uint4*)&Bs[srow][scol]      = rb0;
        *(uint4*)&Bs[64 + srow][scol] = rb1;
        __syncthreads();

        if (k0 + 32 < KDIM) {
            ra0a = *(const float4*)&A[(size_t)(bm + srow)      * KDIM + k0 + 32 + scol];
            ra0b = *(const float4*)&A[(size_t)(bm + srow)      * KDIM + k0 + 36 + scol];
            ra1a = *(const float4*)&A[(size_t)(bm + 64 + srow) * KDIM + k0 + 32 + scol];
            ra1b = *(const float4*)&A[(size_t)(bm + 64 + srow) * KDIM + k0 + 36 + scol];
            rb0  = *(const uint4*)&Wt[(size_t)(bn + srow)      * KDIM + k0 + 32 + scol];
            rb1  = *(const uint4*)&Wt[(size_t)(bn + 64 + srow) * KDIM + k0 + 32 + scol];
        }

        short8 af[4], bf[4];
#pragma unroll
        for (int mi = 0; mi < 4; ++mi)
            af[mi] = *(const short8*)&As[wr + mi * 16 + lrow][lg * 8];
#pragma unroll
        for (int ni = 0; ni < 4; ++ni)
            bf[ni] = *(const short8*)&Bs[wc + ni * 16 + lrow][lg * 8];
#pragma unroll
        for (int mi = 0; mi < 4; ++mi)
#pragma unroll
            for (int ni = 0; ni < 4; ++ni)
                acc[mi][ni] = __builtin_amdgcn_mfma_f32_16x16x32_bf16(
                    af[mi], bf[ni], acc[mi][ni], 0, 0, 0);
    }

#pragma unroll
    for (int ni = 0; ni < 4; ++ni) {
        const int colbase = bn + wc + ni * 16;
        const int which = colbase / C_DIM;
        const int h = (colbase % C_DIM) / HD;
        const int d = (colbase % HD) + lrow;
        const float qs = (which == 0) ? 0.125f : 1.0f;  // fold 1/sqrt(64) into Q
#pragma unroll
        for (int mi = 0; mi < 4; ++mi) {
            const int t0 = bm + wr + mi * 16 + lg * 4;
            const int bb2 = t0 >> 11, tt = t0 & 2047;
            const size_t bhoff = (size_t)(bb2 * NH + h);
            if (which == 2) {
                ushort4 pv;
                pv.x = f2bf(acc[mi][ni][0]); pv.y = f2bf(acc[mi][ni][1]);
                pv.z = f2bf(acc[mi][ni][2]); pv.w = f2bf(acc[mi][ni][3]);
                *(ushort4*)&vtb[(bhoff * HD + d) * T_DIM + tt] = pv;
            } else {
                u16* dst = (which == 0) ? qb : kb;
#pragma unroll
                for (int jj = 0; jj < 4; ++jj)
                    dst[(bhoff * T_DIM + tt + jj) * HD + d] = f2bf(acc[mi][ni][jj] * qs);
            }
        }
    }
}

// ---------------------------------------------------------------------------
// Output projection GEMM: 64x128 tile (384 blocks), BK=32.
// ---------------------------------------------------------------------------
__global__ __launch_bounds__(256) void gemm_proj(
    const u16* __restrict__ A, const u16* __restrict__ Wt,
    float* __restrict__ dense)
{
    __shared__ __align__(16) u16 As[64][40];
    __shared__ __align__(16) u16 Bs[128][40];

    const int tid = threadIdx.x;
    const int bm = blockIdx.y * 64, bn = blockIdx.x * 128;
    const int w = tid >> 6, l = tid & 63;
    const int wr = (w >> 1) * 32, wc = (w & 1) * 64;
    const int lrow = l & 15, lg = l >> 4;

    const int srow = tid >> 2;
    const int scol = (tid & 3) * 8;

    f32x4 acc[2][4];
    const f32x4 zero4 = {0.f, 0.f, 0.f, 0.f};
#pragma unroll
    for (int mi = 0; mi < 2; ++mi)
#pragma unroll
        for (int ni = 0; ni < 4; ++ni) acc[mi][ni] = zero4;

    uint4 ra0 = *(const uint4*)&A [(size_t)(bm + srow)      * KDIM + scol];
    uint4 rb0 = *(const uint4*)&Wt[(size_t)(bn + srow)      * KDIM + scol];
    uint4 rb1 = *(const uint4*)&Wt[(size_t)(bn + 64 + srow) * KDIM + scol];

    for (int k0 = 0; k0 < KDIM; k0 += 32) {
        __syncthreads();
        *(uint4*)&As[srow][scol]      = ra0;
        *(uint4*)&Bs[srow][scol]      = rb0;
        *(uint4*)&Bs[64 + srow][scol] = rb1;
        __syncthreads();

        if (k0 + 32 < KDIM) {
            ra0 = *(const uint4*)&A [(size_t)(bm + srow)      * KDIM + k0 + 32 + scol];
            rb0 = *(const uint4*)&Wt[(size_t)(bn + srow)      * KDIM + k0 + 32 + scol];
            rb1 = *(const uint4*)&Wt[(size_t)(bn + 64 + srow) * KDIM + k0 + 32 + scol];
        }

        short8 af[2], bf[4];
#pragma unroll
        for (int mi = 0; mi < 2; ++mi)
            af[mi] = *(const short8*)&As[wr + mi * 16 + lrow][lg * 8];
#pragma unroll
        for (int ni = 0; ni < 4; ++ni)
            bf[ni] = *(const short8*)&Bs[wc + ni * 16 + lrow][lg * 8];
#pragma unroll
        for (int mi = 0; mi < 2; ++mi)
#pragma unroll
            for (int ni = 0; ni < 4; ++ni)
                acc[mi][ni] = __builtin_amdgcn_mfma_f32_16x16x32_bf16(
                    af[mi], bf[ni], acc[mi][ni], 0, 0, 0);
    }

#pragma unroll
    for (int ni = 0; ni < 4; ++ni) {
        const int col = bn + wc + ni * 16 + lrow;
#pragma unroll
        for (int mi = 0; mi < 2; ++mi) {
            const int m0 = bm + wr + mi * 16 + lg * 4;
#pragma unroll
            for (int jj = 0; jj < 4; ++jj)
                dense[(size_t)(m0 + jj) * C_DIM + col] = acc[mi][ni][jj];
        }
    }
}

// ---------------------------------------------------------------------------
// Flash attention, swapped-QK^T bf16 MFMA. R5 job structure (4 waves/block,
// 512 persistent blocks, dynamic big-first queue). New in R8:
//  - double-buffered LDS K/V tiles staged via global_load_lds (0 staging
//    VGPRs); loads for tile kt+1 issue at round top and land under tile kt's
//    compute; __syncthreads' automatic vmcnt(0) is the (hidden) drain.
//  - linear LDS layouts + XOR chunk swizzle applied to the GLOBAL source
//    (rule: linear dest + inverse-swz source + swz read) -> conflict-free.
//  - both sub-blocks' QK^T MFMAs computed before softmax/PV processing.
// ---------------------------------------------------------------------------
__global__ __launch_bounds__(256, 2) void attn_mfma(
    const u16* __restrict__ q, const u16* __restrict__ k,
    const u16* __restrict__ vt, u16* __restrict__ aw, int* __restrict__ counter)
{
    __shared__ __align__(16) u16 KsL [2][128][64];   // K[t][d], linear
    __shared__ __align__(16) u16 VtsL[2][64][128];   // V^T[d][t], linear
    __shared__ __align__(16) u16 Ps  [4][16][72];    // per-wave P bounce
    __shared__ int job_s;

    const int tid = threadIdx.x, w = tid >> 6, l = tid & 63;
    const int lrow = l & 15, lg = l >> 4;
    const int lr8 = l >> 3, lc8 = l & 7;     // K staging lane split
    const int lr16 = l >> 4, lc16 = l & 15;  // V staging lane split
    const f32x4 zero4 = {0.f, 0.f, 0.f, 0.f};

    for (;;) {
        __syncthreads();                     // prior job's LDS reads done
        if (tid == 0) job_s = atomicAdd(counter, 1);
        __syncthreads();
        const int j = job_s;
        if (j >= NJOBS) break;

        const int qt = 31 - (j / 24);        // big q-tiles first (LPT)
        const int bh = j - (j / 24) * 24;
        const int bb = bh / NH, hh = bh % NH;
        const int qbase = qt * 64 + w * 16;
        const int qg = qbase + lrow;

        const u16* Qp = q  + (size_t)bh * T_DIM * HD;
        const u16* Kp = k  + (size_t)bh * T_DIM * HD;
        const u16* Vp = vt + (size_t)bh * HD * T_DIM;

        const short8 aq0 = *(const short8*)&Qp[(size_t)(qbase + lrow) * HD + lg * 8];
        const short8 aq1 = *(const short8*)&Qp[(size_t)(qbase + lrow) * HD + 32 + lg * 8];

        f32x4 o[4];
#pragma unroll
        for (int n = 0; n < 4; ++n) o[n] = zero4;
        float m_run = -3.0e38f;
        float l_run = 0.0f;

        // async stage of one 128-key tile into buffer `buf`
        auto STAGE = [&](int buf, int kk0) {
#pragma unroll
            for (int i = 0; i < 4; ++i) {            // K: 8 rows (128B) / inst
                const int rb = w * 32 + i * 8;
                const int row = rb + lr8;
                gload16(&Kp[(size_t)(kk0 + row) * HD + ((lc8 ^ (row & 7)) * 8)],
                        &KsL[buf][rb][0]);
            }
#pragma unroll
            for (int i = 0; i < 4; ++i) {            // V^T: 4 rows (256B) / inst
                const int db = w * 16 + i * 4;
                const int d = db + lr16;
                gload16(&Vp[(size_t)d * T_DIM + kk0 + ((lc16 ^ (d & 15)) * 8)],
                        &VtsL[buf][db][0]);
            }
        };

        // one 64-key sub-block: softmax + P bounce + PV
        auto PROCESS = [&](f32x4* s, int sub, int kk0, bool masked) {
            if (masked) {
#pragma unroll
                for (int n = 0; n < 4; ++n)
#pragma unroll
                    for (int jj = 0; jj < 4; ++jj)
                        if (kk0 + sub * 64 + n * 16 + lg * 4 + jj > qg)
                            s[n][jj] = -3.0e38f;
            }
            f32x4 t2 = max4(max4(s[0], s[1]), max4(s[2], s[3]));
            float rm = fmaxf(fmaxf(t2[0], t2[1]), fmaxf(t2[2], t2[3]));
            rm = fmaxf(rm, __shfl_xor(rm, 16));
            rm = fmaxf(rm, __shfl_xor(rm, 32));
            const float m_new = fmaxf(m_run, rm);
            const float alpha = __expf(m_run - m_new);
            m_run = m_new;
#pragma unroll
            for (int n = 0; n < 4; ++n)
#pragma unroll
                for (int jj = 0; jj < 4; ++jj)
                    s[n][jj] = __expf(s[n][jj] - m_new);
            f32x4 a2 = (s[0] + s[1]) + (s[2] + s[3]);
            float rs = (a2[0] + a2[1]) + (a2[2] + a2[3]);
            rs += __shfl_xor(rs, 16);
            rs += __shfl_xor(rs, 32);
            l_run = l_run * alpha + rs;
#pragma unroll
            for (int n = 0; n < 4; ++n) {
                uint2 pr;
                pr.x = cvtpk(s[n][0], s[n][1]);
                pr.y = cvtpk(s[n][2], s[n][3]);
                *(uint2*)&Ps[w][lrow][n * 16 + lg * 4] = pr;
            }
#pragma unroll
            for (int jj = 0; jj < 4; ++jj) {
                const float aj = __shfl(alpha, lg * 4 + jj);
                o[0][jj] *= aj; o[1][jj] *= aj; o[2][jj] *= aj; o[3][jj] *= aj;
            }
            const short8 ap0 = *(const short8*)&Ps[w][lrow][lg * 8];
            const short8 ap1 = *(const short8*)&Ps[w][lrow][32 + lg * 8];
            const int cur = (kk0 >> 7) & 1;
#pragma unroll
            for (int n = 0; n < 4; ++n) {
                const int row = n * 16 + lrow;
                const short8 bv0 = *(const short8*)
                    &VtsL[cur][row][((sub * 8 + lg) ^ lrow) * 8];
                const short8 bv1 = *(const short8*)
                    &VtsL[cur][row][((sub * 8 + 4 + lg) ^ lrow) * 8];
                o[n] = __builtin_amdgcn_mfma_f32_16x16x32_bf16(ap0, bv0, o[n], 0, 0, 0);
                o[n] = __builtin_amdgcn_mfma_f32_16x16x32_bf16(ap1, bv1, o[n], 0, 0, 0);
            }
        };

        const int nkt = qt / 2 + 1;
        int cur = 0;
        STAGE(0, 0);
        for (int kt = 0; kt < nkt; ++kt) {
            const int kk0 = kt * 128;
            __syncthreads();                 // drains this tile's loads (vmcnt)
            if (kt + 1 < nkt) STAGE(cur ^ 1, kk0 + 128);  // lands under compute

            const bool last = (kt == nkt - 1);
            const int nsub = (last && (qt & 1) == 0) ? 1 : 2;

            // ---- QK^T for both sub-blocks upfront (independent MFMA stream)
            f32x4 s0[4], s1[4];
#pragma unroll
            for (int n = 0; n < 4; ++n) {
                const int row = n * 16 + lrow;
                const short8 kf0 = *(const short8*)&KsL[cur][row][((lg)     ^ (lrow & 7)) * 8];
                const short8 kf1 = *(const short8*)&KsL[cur][row][((lg + 4) ^ (lrow & 7)) * 8];
                s0[n] = __builtin_amdgcn_mfma_f32_16x16x32_bf16(kf0, aq0, zero4, 0, 0, 0);
                s0[n] = __builtin_amdgcn_mfma_f32_16x16x32_bf16(kf1, aq1, s0[n], 0, 0, 0);
            }
            if (nsub == 2) {
#pragma unroll
                for (int n = 0; n < 4; ++n) {
                    const int row = 64 + n * 16 + lrow;
                    const short8 kf0 = *(const short8*)&KsL[cur][row][((lg)     ^ (lrow & 7)) * 8];
                    const short8 kf1 = *(const short8*)&KsL[cur][row][((lg + 4) ^ (lrow & 7)) * 8];
                    s1[n] = __builtin_amdgcn_mfma_f32_16x16x32_bf16(kf0, aq0, zero4, 0, 0, 0);
                    s1[n] = __builtin_amdgcn_mfma_f32_16x16x32_bf16(kf1, aq1, s1[n], 0, 0, 0);
                }
            }

            // NOTE: kk0 parity selects cur inside PROCESS ((kk0>>7)&1 == cur)
            PROCESS(s0, 0, kk0, last && nsub == 1);
            if (nsub == 2) PROCESS(s1, 1, kk0, last);

            cur ^= 1;
        }

        // ---- epilogue: normalize, write bf16 [B*T, C]
#pragma unroll
        for (int jj = 0; jj < 4; ++jj) {
            const float lj = __shfl(l_run, lg * 4 + jj);
            const float inv = 1.0f / lj;
            const size_t m = (size_t)bb * T_DIM + qbase + lg * 4 + jj;
#pragma unroll
            for (int n = 0; n < 4; ++n)
                aw[m * C_DIM + hh * HD + n * 16 + lrow] = f2bf(o[n][jj] * inv);
        }
    }
}

// ---------------------------------------------------------------------------
extern "C" void kernel_launch(void* const* d_in, const int* in_sizes, int n_in,
                              void* d_out, int out_size, void* d_ws, size_t ws_size,
                              hipStream_t stream) {
    const float* x      = (const float*)d_in[0];
    const float* W_attn = (const float*)d_in[1];
    const float* W_proj = (const float*)d_in[2];
    float* out = (float*)d_out;

    char* ws = (char*)d_ws;
    u16* wab = (u16*)ws;                       ws += (size_t)NWA * 2;
    u16* wpb = (u16*)ws;                       ws += (size_t)NWP * 2;
    u16* qb  = (u16*)ws;                       ws += (size_t)24 * T_DIM * HD * 2;
    u16* kb  = (u16*)ws;                       ws += (size_t)24 * T_DIM * HD * 2;
    u16* vtb = (u16*)ws;                       ws += (size_t)24 * T_DIM * HD * 2;
    u16* awb = (u16*)ws;                       ws += (size_t)4096 * C_DIM * 2;
    int* cnt = (int*)ws;

    convert_w<<<512, 256, 0, stream>>>(W_attn, W_proj, wab, wpb, cnt);

    gemm_qkv<<<dim3(2304 / 128, 4096 / 128), 256, 0, stream>>>(
        x, wab, qb, kb, vtb);

    attn_mfma<<<512, 256, 0, stream>>>(qb, kb, vtb, awb, cnt);

    gemm_proj<<<dim3(768 / 128, 4096 / 64), 256, 0, stream>>>(
        awb, wpb, out);
}

// Round 9
// 95.773 us; speedup vs baseline: 2.1070x; 1.1244x over previous
//
#include <hip/hip_runtime.h>

#define T_DIM 2048
#define C_DIM 768
#define NH    12
#define HD    64
#define KDIM  768
#define NJOBS (24 * 32)

typedef __attribute__((ext_vector_type(8))) short short8;
typedef __attribute__((ext_vector_type(4))) float f32x4;
typedef unsigned short u16;

__device__ __forceinline__ u16 f2bf(float f) {
    unsigned int u = __builtin_bit_cast(unsigned int, f);
    u = (u + 0x7fffu + ((u >> 16) & 1u)) >> 16;   // RNE
    return (u16)u;
}
__device__ __forceinline__ f32x4 max4(f32x4 a, f32x4 b) {
    f32x4 r; r[0]=fmaxf(a[0],b[0]); r[1]=fmaxf(a[1],b[1]);
    r[2]=fmaxf(a[2],b[2]); r[3]=fmaxf(a[3],b[3]); return r;
}
__device__ __forceinline__ unsigned int cvtpk(float a, float b) {
    unsigned int r;
    asm("v_cvt_pk_bf16_f32 %0, %1, %2" : "=v"(r) : "v"(a), "v"(b));
    return r;
}
// async global->LDS, 16B per lane; LDS dest = wave-uniform base + lane*16
__device__ __forceinline__ void gload16(const u16* g, u16* l) {
    __builtin_amdgcn_global_load_lds(
        (const __attribute__((address_space(1))) unsigned int*)g,
        (__attribute__((address_space(3))) unsigned int*)l, 16, 0, 0);
}

// ---------------------------------------------------------------------------
// fp32 -> bf16 conversion of x, W_attn, W_proj; zeroes the attn job counter.
// ---------------------------------------------------------------------------
#define NX  (4096 * 768)
#define NWA (2304 * 768)
#define NWP (768 * 768)
#define TOT4 ((NX + NWA + NWP) / 4)

__global__ __launch_bounds__(256) void convert_all(
    const float* __restrict__ x, const float* __restrict__ wa,
    const float* __restrict__ wp, u16* __restrict__ xb,
    u16* __restrict__ wab, u16* __restrict__ wpb, int* __restrict__ counter)
{
    if (blockIdx.x == 0 && threadIdx.x == 0) *counter = 0;
    for (int i4 = blockIdx.x * 256 + threadIdx.x; i4 < TOT4; i4 += gridDim.x * 256) {
        int i = i4 * 4;
        const float* src; u16* dst; int off;
        if (i < NX)            { src = x;  dst = xb;  off = i; }
        else if (i < NX + NWA) { src = wa; dst = wab; off = i - NX; }
        else                   { src = wp; dst = wpb; off = i - NX - NWA; }
        float4 v = *(const float4*)&src[off];
        ushort4 o;
        o.x = f2bf(v.x); o.y = f2bf(v.y); o.z = f2bf(v.z); o.w = f2bf(v.w);
        *(ushort4*)&dst[off] = o;
    }
}

// ---------------------------------------------------------------------------
// QKV GEMM, m97-style: bf16 A and W; global_load_lds staging into
// double-buffered linear LDS [128][32] with XOR-4 source pre-swizzle;
// XCD-aware stripe-major block mapping (576 blocks = 8 XCDs x 4 stripes x 18
// column tiles: each XCD's L2 fetches its 4 x-stripes once).
// Scatter epilogue -> q (x1/8), k, vT.
// ---------------------------------------------------------------------------
__global__ __launch_bounds__(256) void gemm_qkv(
    const u16* __restrict__ A, const u16* __restrict__ Wt,
    u16* __restrict__ qb, u16* __restrict__ kb, u16* __restrict__ vtb)
{
    __shared__ __align__(16) u16 AsL[2][128][32];
    __shared__ __align__(16) u16 BsL[2][128][32];

    const int tid = threadIdx.x;
    const int orig = blockIdx.x;                 // 576 = 72 * 8
    const int wg = (orig & 7) * 72 + (orig >> 3);  // XCD-contiguous (m157, bijective)
    const int bm = (wg / 18) * 128;              // stripe-major within XCD
    const int bn = (wg % 18) * 128;

    const int w = tid >> 6, l = tid & 63;
    const int wr = (w >> 1) * 64, wc = (w & 1) * 64;
    const int lrow = l & 15, lg = l >> 4;
    const int lr4 = l >> 2, lc4 = l & 3;         // staging lane split (16 rows/inst)

    f32x4 acc[4][4];
    const f32x4 zero4 = {0.f, 0.f, 0.f, 0.f};
#pragma unroll
    for (int mi = 0; mi < 4; ++mi)
#pragma unroll
        for (int ni = 0; ni < 4; ++ni) acc[mi][ni] = zero4;

    // stage one BK=32 K-slice of A and W into buffer `buf`
    auto STAGE = [&](int buf, int k0) {
#pragma unroll
        for (int i = 0; i < 2; ++i) {
            const int rb = w * 32 + i * 16;      // wave-uniform dest row base
            const int row = rb + lr4;
            const int sc = (lc4 ^ (row & 3)) * 8;  // inverse-swizzled source chunk
            gload16(&A [(size_t)(bm + row) * KDIM + k0 + sc], &AsL[buf][rb][0]);
            gload16(&Wt[(size_t)(bn + row) * KDIM + k0 + sc], &BsL[buf][rb][0]);
        }
    };

    int cur = 0;
    STAGE(0, 0);
    for (int k0 = 0; k0 < KDIM; k0 += 32) {
        __syncthreads();                         // drains cur's loads (vmcnt@barrier)
        if (k0 + 32 < KDIM) STAGE(cur ^ 1, k0 + 32);   // lands under compute

        short8 af[4], bf[4];
#pragma unroll
        for (int mi = 0; mi < 4; ++mi)
            af[mi] = *(const short8*)&AsL[cur][wr + mi * 16 + lrow][(lg ^ (lrow & 3)) * 8];
#pragma unroll
        for (int ni = 0; ni < 4; ++ni)
            bf[ni] = *(const short8*)&BsL[cur][wc + ni * 16 + lrow][(lg ^ (lrow & 3)) * 8];
#pragma unroll
        for (int mi = 0; mi < 4; ++mi)
#pragma unroll
            for (int ni = 0; ni < 4; ++ni)
                acc[mi][ni] = __builtin_amdgcn_mfma_f32_16x16x32_bf16(
                    af[mi], bf[ni], acc[mi][ni], 0, 0, 0);
        cur ^= 1;
    }

#pragma unroll
    for (int ni = 0; ni < 4; ++ni) {
        const int colbase = bn + wc + ni * 16;
        const int which = colbase / C_DIM;
        const int h = (colbase % C_DIM) / HD;
        const int d = (colbase % HD) + lrow;
        const float qs = (which == 0) ? 0.125f : 1.0f;  // fold 1/sqrt(64) into Q
#pragma unroll
        for (int mi = 0; mi < 4; ++mi) {
            const int t0 = bm + wr + mi * 16 + lg * 4;
            const int bb2 = t0 >> 11, tt = t0 & 2047;
            const size_t bhoff = (size_t)(bb2 * NH + h);
            if (which == 2) {
                ushort4 pv;
                pv.x = f2bf(acc[mi][ni][0]); pv.y = f2bf(acc[mi][ni][1]);
                pv.z = f2bf(acc[mi][ni][2]); pv.w = f2bf(acc[mi][ni][3]);
                *(ushort4*)&vtb[(bhoff * HD + d) * T_DIM + tt] = pv;
            } else {
                u16* dst = (which == 0) ? qb : kb;
#pragma unroll
                for (int jj = 0; jj < 4; ++jj)
                    dst[(bhoff * T_DIM + tt + jj) * HD + d] = f2bf(acc[mi][ni][jj] * qs);
            }
        }
    }
}

// ---------------------------------------------------------------------------
// Output projection GEMM: 64x128 tile, XCD-aware mapping (384 = 48*8), BK=32.
// ---------------------------------------------------------------------------
__global__ __launch_bounds__(256) void gemm_proj(
    const u16* __restrict__ A, const u16* __restrict__ Wt,
    float* __restrict__ dense)
{
    __shared__ __align__(16) u16 As[64][40];
    __shared__ __align__(16) u16 Bs[128][40];

    const int tid = threadIdx.x;
    const int orig = blockIdx.x;                 // 384 = 48 * 8
    const int wg = (orig & 7) * 48 + (orig >> 3);
    const int bm = (wg / 6) * 64, bn = (wg % 6) * 128;

    const int w = tid >> 6, l = tid & 63;
    const int wr = (w >> 1) * 32, wc = (w & 1) * 64;
    const int lrow = l & 15, lg = l >> 4;

    const int srow = tid >> 2;
    const int scol = (tid & 3) * 8;

    f32x4 acc[2][4];
    const f32x4 zero4 = {0.f, 0.f, 0.f, 0.f};
#pragma unroll
    for (int mi = 0; mi < 2; ++mi)
#pragma unroll
        for (int ni = 0; ni < 4; ++ni) acc[mi][ni] = zero4;

    uint4 ra0 = *(const uint4*)&A [(size_t)(bm + srow)      * KDIM + scol];
    uint4 rb0 = *(const uint4*)&Wt[(size_t)(bn + srow)      * KDIM + scol];
    uint4 rb1 = *(const uint4*)&Wt[(size_t)(bn + 64 + srow) * KDIM + scol];

    for (int k0 = 0; k0 < KDIM; k0 += 32) {
        __syncthreads();
        *(uint4*)&As[srow][scol]      = ra0;
        *(uint4*)&Bs[srow][scol]      = rb0;
        *(uint4*)&Bs[64 + srow][scol] = rb1;
        __syncthreads();

        if (k0 + 32 < KDIM) {
            ra0 = *(const uint4*)&A [(size_t)(bm + srow)      * KDIM + k0 + 32 + scol];
            rb0 = *(const uint4*)&Wt[(size_t)(bn + srow)      * KDIM + k0 + 32 + scol];
            rb1 = *(const uint4*)&Wt[(size_t)(bn + 64 + srow) * KDIM + k0 + 32 + scol];
        }

        short8 af[2], bf[4];
#pragma unroll
        for (int mi = 0; mi < 2; ++mi)
            af[mi] = *(const short8*)&As[wr + mi * 16 + lrow][lg * 8];
#pragma unroll
        for (int ni = 0; ni < 4; ++ni)
            bf[ni] = *(const short8*)&Bs[wc + ni * 16 + lrow][lg * 8];
#pragma unroll
        for (int mi = 0; mi < 2; ++mi)
#pragma unroll
            for (int ni = 0; ni < 4; ++ni)
                acc[mi][ni] = __builtin_amdgcn_mfma_f32_16x16x32_bf16(
                    af[mi], bf[ni], acc[mi][ni], 0, 0, 0);
    }

#pragma unroll
    for (int ni = 0; ni < 4; ++ni) {
        const int col = bn + wc + ni * 16 + lrow;
#pragma unroll
        for (int mi = 0; mi < 2; ++mi) {
            const int m0 = bm + wr + mi * 16 + lg * 4;
#pragma unroll
            for (int jj = 0; jj < 4; ++jj)
                dense[(size_t)(m0 + jj) * C_DIM + col] = acc[mi][ni][jj];
        }
    }
}

// ---------------------------------------------------------------------------
// Flash attention — unchanged from R8 (49 us): swapped-QK^T, 4 waves/block,
// 512 persistent blocks w/ dynamic big-first queue, global_load_lds
// double-buffered K/V tiles, XOR source swizzle, both QK^T sub-blocks upfront.
// ---------------------------------------------------------------------------
__global__ __launch_bounds__(256, 2) void attn_mfma(
    const u16* __restrict__ q, const u16* __restrict__ k,
    const u16* __restrict__ vt, u16* __restrict__ aw, int* __restrict__ counter)
{
    __shared__ __align__(16) u16 KsL [2][128][64];   // K[t][d], linear
    __shared__ __align__(16) u16 VtsL[2][64][128];   // V^T[d][t], linear
    __shared__ __align__(16) u16 Ps  [4][16][72];    // per-wave P bounce
    __shared__ int job_s;

    const int tid = threadIdx.x, w = tid >> 6, l = tid & 63;
    const int lrow = l & 15, lg = l >> 4;
    const int lr8 = l >> 3, lc8 = l & 7;     // K staging lane split
    const int lr16 = l >> 4, lc16 = l & 15;  // V staging lane split
    const f32x4 zero4 = {0.f, 0.f, 0.f, 0.f};

    for (;;) {
        __syncthreads();                     // prior job's LDS reads done
        if (tid == 0) job_s = atomicAdd(counter, 1);
        __syncthreads();
        const int j = job_s;
        if (j >= NJOBS) break;

        const int qt = 31 - (j / 24);        // big q-tiles first (LPT)
        const int bh = j - (j / 24) * 24;
        const int bb = bh / NH, hh = bh % NH;
        const int qbase = qt * 64 + w * 16;
        const int qg = qbase + lrow;

        const u16* Qp = q  + (size_t)bh * T_DIM * HD;
        const u16* Kp = k  + (size_t)bh * T_DIM * HD;
        const u16* Vp = vt + (size_t)bh * HD * T_DIM;

        const short8 aq0 = *(const short8*)&Qp[(size_t)(qbase + lrow) * HD + lg * 8];
        const short8 aq1 = *(const short8*)&Qp[(size_t)(qbase + lrow) * HD + 32 + lg * 8];

        f32x4 o[4];
#pragma unroll
        for (int n = 0; n < 4; ++n) o[n] = zero4;
        float m_run = -3.0e38f;
        float l_run = 0.0f;

        auto STAGE = [&](int buf, int kk0) {
#pragma unroll
            for (int i = 0; i < 4; ++i) {            // K: 8 rows (128B) / inst
                const int rb = w * 32 + i * 8;
                const int row = rb + lr8;
                gload16(&Kp[(size_t)(kk0 + row) * HD + ((lc8 ^ (row & 7)) * 8)],
                        &KsL[buf][rb][0]);
            }
#pragma unroll
            for (int i = 0; i < 4; ++i) {            // V^T: 4 rows (256B) / inst
                const int db = w * 16 + i * 4;
                const int d = db + lr16;
                gload16(&Vp[(size_t)d * T_DIM + kk0 + ((lc16 ^ (d & 15)) * 8)],
                        &VtsL[buf][db][0]);
            }
        };

        auto PROCESS = [&](f32x4* s, int sub, int kk0, bool masked) {
            if (masked) {
#pragma unroll
                for (int n = 0; n < 4; ++n)
#pragma unroll
                    for (int jj = 0; jj < 4; ++jj)
                        if (kk0 + sub * 64 + n * 16 + lg * 4 + jj > qg)
                            s[n][jj] = -3.0e38f;
            }
            f32x4 t2 = max4(max4(s[0], s[1]), max4(s[2], s[3]));
            float rm = fmaxf(fmaxf(t2[0], t2[1]), fmaxf(t2[2], t2[3]));
            rm = fmaxf(rm, __shfl_xor(rm, 16));
            rm = fmaxf(rm, __shfl_xor(rm, 32));
            const float m_new = fmaxf(m_run, rm);
            const float alpha = __expf(m_run - m_new);
            m_run = m_new;
#pragma unroll
            for (int n = 0; n < 4; ++n)
#pragma unroll
                for (int jj = 0; jj < 4; ++jj)
                    s[n][jj] = __expf(s[n][jj] - m_new);
            f32x4 a2 = (s[0] + s[1]) + (s[2] + s[3]);
            float rs = (a2[0] + a2[1]) + (a2[2] + a2[3]);
            rs += __shfl_xor(rs, 16);
            rs += __shfl_xor(rs, 32);
            l_run = l_run * alpha + rs;
#pragma unroll
            for (int n = 0; n < 4; ++n) {
                uint2 pr;
                pr.x = cvtpk(s[n][0], s[n][1]);
                pr.y = cvtpk(s[n][2], s[n][3]);
                *(uint2*)&Ps[w][lrow][n * 16 + lg * 4] = pr;
            }
#pragma unroll
            for (int jj = 0; jj < 4; ++jj) {
                const float aj = __shfl(alpha, lg * 4 + jj);
                o[0][jj] *= aj; o[1][jj] *= aj; o[2][jj] *= aj; o[3][jj] *= aj;
            }
            const short8 ap0 = *(const short8*)&Ps[w][lrow][lg * 8];
            const short8 ap1 = *(const short8*)&Ps[w][lrow][32 + lg * 8];
            const int cur = (kk0 >> 7) & 1;
#pragma unroll
            for (int n = 0; n < 4; ++n) {
                const int row = n * 16 + lrow;
                const short8 bv0 = *(const short8*)
                    &VtsL[cur][row][((sub * 8 + lg) ^ lrow) * 8];
                const short8 bv1 = *(const short8*)
                    &VtsL[cur][row][((sub * 8 + 4 + lg) ^ lrow) * 8];
                o[n] = __builtin_amdgcn_mfma_f32_16x16x32_bf16(ap0, bv0, o[n], 0, 0, 0);
                o[n] = __builtin_amdgcn_mfma_f32_16x16x32_bf16(ap1, bv1, o[n], 0, 0, 0);
            }
        };

        const int nkt = qt / 2 + 1;
        int cur = 0;
        STAGE(0, 0);
        for (int kt = 0; kt < nkt; ++kt) {
            const int kk0 = kt * 128;
            __syncthreads();                 // drains this tile's loads (vmcnt)
            if (kt + 1 < nkt) STAGE(cur ^ 1, kk0 + 128);  // lands under compute

            const bool last = (kt == nkt - 1);
            const int nsub = (last && (qt & 1) == 0) ? 1 : 2;

            f32x4 s0[4], s1[4];
#pragma unroll
            for (int n = 0; n < 4; ++n) {
                const int row = n * 16 + lrow;
                const short8 kf0 = *(const short8*)&KsL[cur][row][((lg)     ^ (lrow & 7)) * 8];
                const short8 kf1 = *(const short8*)&KsL[cur][row][((lg + 4) ^ (lrow & 7)) * 8];
                s0[n] = __builtin_amdgcn_mfma_f32_16x16x32_bf16(kf0, aq0, zero4, 0, 0, 0);
                s0[n] = __builtin_amdgcn_mfma_f32_16x16x32_bf16(kf1, aq1, s0[n], 0, 0, 0);
            }
            if (nsub == 2) {
#pragma unroll
                for (int n = 0; n < 4; ++n) {
                    const int row = 64 + n * 16 + lrow;
                    const short8 kf0 = *(const short8*)&KsL[cur][row][((lg)     ^ (lrow & 7)) * 8];
                    const short8 kf1 = *(const short8*)&KsL[cur][row][((lg + 4) ^ (lrow & 7)) * 8];
                    s1[n] = __builtin_amdgcn_mfma_f32_16x16x32_bf16(kf0, aq0, zero4, 0, 0, 0);
                    s1[n] = __builtin_amdgcn_mfma_f32_16x16x32_bf16(kf1, aq1, s1[n], 0, 0, 0);
                }
            }

            PROCESS(s0, 0, kk0, last && nsub == 1);
            if (nsub == 2) PROCESS(s1, 1, kk0, last);

            cur ^= 1;
        }

#pragma unroll
        for (int jj = 0; jj < 4; ++jj) {
            const float lj = __shfl(l_run, lg * 4 + jj);
            const float inv = 1.0f / lj;
            const size_t m = (size_t)bb * T_DIM + qbase + lg * 4 + jj;
#pragma unroll
            for (int n = 0; n < 4; ++n)
                aw[m * C_DIM + hh * HD + n * 16 + lrow] = f2bf(o[n][jj] * inv);
        }
    }
}

// ---------------------------------------------------------------------------
extern "C" void kernel_launch(void* const* d_in, const int* in_sizes, int n_in,
                              void* d_out, int out_size, void* d_ws, size_t ws_size,
                              hipStream_t stream) {
    const float* x      = (const float*)d_in[0];
    const float* W_attn = (const float*)d_in[1];
    const float* W_proj = (const float*)d_in[2];
    float* out = (float*)d_out;

    char* ws = (char*)d_ws;
    u16* xb  = (u16*)ws;                       ws += (size_t)NX * 2;
    u16* wab = (u16*)ws;                       ws += (size_t)NWA * 2;
    u16* wpb = (u16*)ws;                       ws += (size_t)NWP * 2;
    u16* qb  = (u16*)ws;                       ws += (size_t)24 * T_DIM * HD * 2;
    u16* kb  = (u16*)ws;                       ws += (size_t)24 * T_DIM * HD * 2;
    u16* vtb = (u16*)ws;                       ws += (size_t)24 * T_DIM * HD * 2;
    u16* awb = (u16*)ws;                       ws += (size_t)4096 * C_DIM * 2;
    int* cnt = (int*)ws;

    convert_all<<<2048, 256, 0, stream>>>(x, W_attn, W_proj, xb, wab, wpb, cnt);

    gemm_qkv<<<576, 256, 0, stream>>>(xb, wab, qb, kb, vtb);

    attn_mfma<<<512, 256, 0, stream>>>(qb, kb, vtb, awb, cnt);

    gemm_proj<<<384, 256, 0, stream>>>(awb, wpb, out);
}